// Round 23
// baseline (65.958 us; speedup 1.0000x reference)
//
#include <hip/hip_runtime.h>
#include <hip/hip_fp16.h>

#define HOP 256
#define CUT 513
#define T_FRAMES 1021
#define N_SAMPLES 262144
#define BATCH 16
#define BLKS_PER_B 64              // 16 frames per block
#define NWG (BATCH * BLKS_PER_B)   // 1024, divisible by 8
#define FLAG_T 0.01f               // phase-risk flag threshold

// 6-bit bit reversal
__device__ __forceinline__ int bitrev6(int v) {
    return ((v & 1) << 5) | ((v & 2) << 3) | ((v & 4) << 1)
         | ((v & 8) >> 1) | ((v & 16) >> 3) | ((v & 32) >> 5);
}
// LDS slot for (k, tt in 0..15): stride 17 + XOR swizzle (bijective per k)
__device__ __forceinline__ int slot17(int k, int tt) {
    return 17 * k + (tt ^ ((k >> 4) & 15));
}
// W_1024^k as (cos,sin), arg in revolutions [R7-verified]
__device__ __forceinline__ float2 twid(float rev) {
    return make_float2(__builtin_amdgcn_cosf(rev), __builtin_amdgcn_sinf(rev));
}
__device__ __forceinline__ float2 cmulwf(float yr, float yi, float2 w) {
    return make_float2(yr * w.x + yi * w.y, yi * w.x - yr * w.y);
}
// fast atan2 [R13-verified]
__device__ __forceinline__ float fast_atan2f(float y, float x) {
    const float PI  = 3.14159265358979323846f;
    const float PI2 = 1.57079632679489661923f;
    float ay = __builtin_fabsf(y), ax = __builtin_fabsf(x);
    float mx = fmaxf(ax, ay), mn = fminf(ax, ay);
    float r  = mn * __builtin_amdgcn_rcpf(mx);
    float s  = r * r;
    float p  = r * (0.99997726f + s * (-0.33262347f + s * (0.19354346f
             + s * (-0.11643287f + s * (0.05265332f + s * (-0.01172120f))))));
    p = (ay > ax) ? (PI2 - p) : p;
    p = (x < 0.0f) ? (PI - p) : p;
    return __builtin_copysignf(p, y);
}
// fp64 (cos,sin) of 2*pi*e/1024 [R16-verified]
__device__ __forceinline__ double2 wexp64(int e) {
    const int d = e & 63, c = (e >> 6) & 3, a = (e >> 8) & 3;
    double xx = (6.2831853071795864769252867665590057684 / 1024.0) * (double)d;
    double x2 = xx * xx;
    double cc = 1.0 + x2 * (-0.5 + x2 * (1.0/24.0 + x2 * (-1.0/720.0
               + x2 * (1.0/40320.0 + x2 * (-1.0/3628800.0)))));
    double ss = xx * (1.0 + x2 * (-1.0/6.0 + x2 * (1.0/120.0 + x2 * (-1.0/5040.0
               + x2 * (1.0/362880.0 + x2 * (-1.0/39916800.0))))));
    double kc = (c == 0) ? 1.0
              : (c == 1) ? 0.92387953251128675612818318939679
              : (c == 2) ? 0.70710678118654752440084436210485
                         : 0.38268343236508977172845998403040;
    double ks = (c == 0) ? 0.0
              : (c == 1) ? 0.38268343236508977172845998403040
              : (c == 2) ? 0.70710678118654752440084436210485
                         : 0.92387953251128675612818318939679;
    double cr = cc * kc - ss * ks;
    double ci = ss * kc + cc * ks;
    double2 r;
    r.x = (a == 0) ? cr : ((a == 1) ? -ci : ((a == 2) ? -cr : ci));
    r.y = (a == 0) ? ci : ((a == 1) ?  cr : ((a == 2) ? -ci : -cr));
    return r;
}

__global__ __launch_bounds__(256, 2) void stft_fft_kernel(
    const float* __restrict__ x,
    const float* __restrict__ basis,
    float* __restrict__ out)
{
    // fp16-packed staging (.x = mag, .y = phase), 16 t-columns: 34948 B
    __shared__ __half2 sbuf[17 * CUT + 16];

    const int tid  = threadIdx.x;
    const int lane = tid & 63;
    const int wv   = tid >> 6;             // 0..3

    // XCD-chunked bijective swizzle (1024 % 8 == 0)
    const int sb  = (blockIdx.x & 7) * (NWG / 8) + (blockIdx.x >> 3);
    const int b   = sb >> 6;               // batch
    const int blk = sb & 63;
    const int tb  = blk * 16;              // block's 16-frame base
    const int t0  = tb + 4 * wv;           // wave's 4 frames (2 packed FFTs)
    const bool v1 = (t0 + 1) < T_FRAMES;
    const bool v2 = (t0 + 2) < T_FRAMES;
    const bool v3 = (t0 + 3) < T_FRAMES;

    const float* xptr  = x + (size_t)b * N_SAMPLES + (size_t)t0 * HOP;
    const float* wrow  = basis;                       // row 0 == Hann window
    const float* nyrow = basis + 1025 * 1024;         // imag Nyquist row
    const int rem = N_SAMPLES - t0 * HOP;             // bounds clamp for tail

    float2 z1[16], z2[16];
    float IA = 0.f, IB = 0.f, IC = 0.f, ID = 0.f;
    double pA = 0.0, pB = 0.0, pC = 0.0, pD = 0.0;    // fp64 sum(w*x) partials
    float xv[8];

    // ================= z1: frames t0, t0+1 (R21-verified 8-reg plan) ======
    #define LD1(j) (((64 * (j) + lane) < rem) ? xptr[64 * (j) + lane] : 0.0f)
    #pragma unroll
    for (int j = 0; j < 8; ++j) xv[j] = LD1(j);
    #pragma unroll
    for (int r = 0; r < 4; ++r) {
        int n = 64 * r + lane;
        float wn = wrow[n], cn = nyrow[n];
        float xa = xv[r], xb2 = xv[r + 4];
        z1[r] = make_float2(wn * xa, wn * xb2);
        IA += cn * xa;  IB += cn * xb2;
        pA += (double)wn * (double)xa;  pB += (double)wn * (double)xb2;
    }
    #pragma unroll
    for (int j = 0; j < 4; ++j) xv[j] = LD1(8 + j);
    #pragma unroll
    for (int r = 4; r < 8; ++r) {
        int n = 64 * r + lane;
        float wn = wrow[n], cn = nyrow[n];
        float xa = xv[r], xb2 = xv[r - 4];
        z1[r] = make_float2(wn * xa, wn * xb2);
        IA += cn * xa;  IB += cn * xb2;
        pA += (double)wn * (double)xa;  pB += (double)wn * (double)xb2;
    }
    #pragma unroll
    for (int j = 4; j < 8; ++j) xv[j] = LD1(8 + j);
    #pragma unroll
    for (int r = 8; r < 12; ++r) {
        int n = 64 * r + lane;
        float wn = wrow[n], cn = nyrow[n];
        float xa = xv[r - 8], xb2 = xv[r - 4];
        z1[r] = make_float2(wn * xa, wn * xb2);
        IA += cn * xa;  IB += cn * xb2;
        pA += (double)wn * (double)xa;  pB += (double)wn * (double)xb2;
    }
    #pragma unroll
    for (int j = 0; j < 4; ++j) xv[j] = LD1(16 + j);
    #pragma unroll
    for (int r = 12; r < 16; ++r) {
        int n = 64 * r + lane;
        float wn = wrow[n], cn = nyrow[n];
        float xa = xv[r - 8], xb2 = xv[r - 12];
        z1[r] = make_float2(wn * xa, wn * xb2);
        IA += cn * xa;  IB += cn * xb2;
        pA += (double)wn * (double)xa;  pB += (double)wn * (double)xb2;
    }

    // ================= z2: frames t0+2, t0+3 (same plan, +512 samples) ====
    #define LD2(j) (((512 + 64 * (j) + lane) < rem) ? xptr[512 + 64 * (j) + lane] : 0.0f)
    #pragma unroll
    for (int j = 0; j < 8; ++j) xv[j] = LD2(j);
    #pragma unroll
    for (int r = 0; r < 4; ++r) {
        int n = 64 * r + lane;
        float wn = wrow[n], cn = nyrow[n];
        float xa = xv[r], xb2 = xv[r + 4];
        z2[r] = make_float2(wn * xa, wn * xb2);
        IC += cn * xa;  ID += cn * xb2;
        pC += (double)wn * (double)xa;  pD += (double)wn * (double)xb2;
    }
    #pragma unroll
    for (int j = 0; j < 4; ++j) xv[j] = LD2(8 + j);
    #pragma unroll
    for (int r = 4; r < 8; ++r) {
        int n = 64 * r + lane;
        float wn = wrow[n], cn = nyrow[n];
        float xa = xv[r], xb2 = xv[r - 4];
        z2[r] = make_float2(wn * xa, wn * xb2);
        IC += cn * xa;  ID += cn * xb2;
        pC += (double)wn * (double)xa;  pD += (double)wn * (double)xb2;
    }
    #pragma unroll
    for (int j = 4; j < 8; ++j) xv[j] = LD2(8 + j);
    #pragma unroll
    for (int r = 8; r < 12; ++r) {
        int n = 64 * r + lane;
        float wn = wrow[n], cn = nyrow[n];
        float xa = xv[r - 8], xb2 = xv[r - 4];
        z2[r] = make_float2(wn * xa, wn * xb2);
        IC += cn * xa;  ID += cn * xb2;
        pC += (double)wn * (double)xa;  pD += (double)wn * (double)xb2;
    }
    #pragma unroll
    for (int j = 0; j < 4; ++j) xv[j] = LD2(16 + j);
    #pragma unroll
    for (int r = 12; r < 16; ++r) {
        int n = 64 * r + lane;
        float wn = wrow[n], cn = nyrow[n];
        float xa = xv[r - 8], xb2 = xv[r - 12];
        z2[r] = make_float2(wn * xa, wn * xb2);
        IC += cn * xa;  ID += cn * xb2;
        pC += (double)wn * (double)xa;  pD += (double)wn * (double)xb2;
    }

    // ---- Nyquist-re via pair-diff [R19-verified]; DC side-channel dropped
    {
        double qA = __shfl_xor(pA, 1), qB = __shfl_xor(pB, 1);
        double qC = __shfl_xor(pC, 1), qD = __shfl_xor(pD, 1);
        pA = (lane & 1) ? (qA - pA) : (pA - qA);   // now holds nr partials
        pB = (lane & 1) ? (qB - pB) : (pB - qB);
        pC = (lane & 1) ? (qC - pC) : (pC - qC);
        pD = (lane & 1) ? (qD - pD) : (pD - qD);
        #pragma unroll
        for (int off = 2; off <= 32; off <<= 1) {
            pA += __shfl_xor(pA, off); pB += __shfl_xor(pB, off);
            pC += __shfl_xor(pC, off); pD += __shfl_xor(pD, off);
        }
        #pragma unroll
        for (int off = 32; off > 0; off >>= 1) {
            IA += __shfl_xor(IA, off); IB += __shfl_xor(IB, off);
            IC += __shfl_xor(IC, off); ID += __shfl_xor(ID, off);
        }
    }

    // ---- stage 0: radix-4 DIF stride 256, shared twiddles [R18-verified]
    #pragma unroll
    for (int r0 = 0; r0 < 4; ++r0) {
        float nf = (float)(64 * r0 + lane);
        float2 w1 = twid(nf * (1.0f / 1024.0f));
        float2 w2 = twid(nf * (2.0f / 1024.0f));
        float2 w3 = twid(nf * (3.0f / 1024.0f));
        {
            float2 A = z1[r0], B = z1[r0+4], C = z1[r0+8], D = z1[r0+12];
            float t0r = A.x+C.x, t0i = A.y+C.y, t1r = A.x-C.x, t1i = A.y-C.y;
            float t2r = B.x+D.x, t2i = B.y+D.y, t3r = B.x-D.x, t3i = B.y-D.y;
            z1[r0]      = make_float2(t0r+t2r, t0i+t2i);
            z1[r0 + 4]  = cmulwf(t1r+t3i, t1i-t3r, w1);
            z1[r0 + 8]  = cmulwf(t0r-t2r, t0i-t2i, w2);
            z1[r0 + 12] = cmulwf(t1r-t3i, t1i+t3r, w3);
        }
        {
            float2 A = z2[r0], B = z2[r0+4], C = z2[r0+8], D = z2[r0+12];
            float t0r = A.x+C.x, t0i = A.y+C.y, t1r = A.x-C.x, t1i = A.y-C.y;
            float t2r = B.x+D.x, t2i = B.y+D.y, t3r = B.x-D.x, t3i = B.y-D.y;
            z2[r0]      = make_float2(t0r+t2r, t0i+t2i);
            z2[r0 + 4]  = cmulwf(t1r+t3i, t1i-t3r, w1);
            z2[r0 + 8]  = cmulwf(t0r-t2r, t0i-t2i, w2);
            z2[r0 + 12] = cmulwf(t1r-t3i, t1i+t3r, w3);
        }
    }

    // ---- stage 1: radix-4 DIF stride 64, shared twiddles [R18-verified]
    {
        float fl = (float)lane;
        float2 w1 = twid(fl * (4.0f / 1024.0f));
        float2 w2 = twid(fl * (8.0f / 1024.0f));
        float2 w3 = twid(fl * (12.0f / 1024.0f));
        #pragma unroll
        for (int g = 0; g < 4; ++g) {
            {
                float2 A = z1[4*g], B = z1[4*g+1], C = z1[4*g+2], D = z1[4*g+3];
                float t0r = A.x+C.x, t0i = A.y+C.y, t1r = A.x-C.x, t1i = A.y-C.y;
                float t2r = B.x+D.x, t2i = B.y+D.y, t3r = B.x-D.x, t3i = B.y-D.y;
                z1[4*g]     = make_float2(t0r+t2r, t0i+t2i);
                z1[4*g + 1] = cmulwf(t1r+t3i, t1i-t3r, w1);
                z1[4*g + 2] = cmulwf(t0r-t2r, t0i-t2i, w2);
                z1[4*g + 3] = cmulwf(t1r-t3i, t1i+t3r, w3);
            }
            {
                float2 A = z2[4*g], B = z2[4*g+1], C = z2[4*g+2], D = z2[4*g+3];
                float t0r = A.x+C.x, t0i = A.y+C.y, t1r = A.x-C.x, t1i = A.y-C.y;
                float t2r = B.x+D.x, t2i = B.y+D.y, t3r = B.x-D.x, t3i = B.y-D.y;
                z2[4*g]     = make_float2(t0r+t2r, t0i+t2i);
                z2[4*g + 1] = cmulwf(t1r+t3i, t1i-t3r, w1);
                z2[4*g + 2] = cmulwf(t0r-t2r, t0i-t2i, w2);
                z2[4*g + 3] = cmulwf(t1r-t3i, t1i+t3r, w3);
            }
        }
    }

    // ---- stages 2..7: radix-2 across lanes, branchless, interleaved
    #pragma unroll
    for (int st = 0; st < 6; ++st) {
        const int h = 32 >> st;
        const bool hi = (lane & h) != 0;
        float2 t = twid((float)(lane & (h-1)) * ((float)(512/h) * (1.0f/1024.0f)));
        float wx = hi ? t.x : 1.0f;
        float wy = hi ? t.y : 0.0f;
        const float sgnD = hi ? -1.0f : 1.0f;
        #pragma unroll
        for (int r = 0; r < 16; ++r) {
            float vr = __shfl_xor(z1[r].x, h);
            float vi = __shfl_xor(z1[r].y, h);
            float sr = sgnD * z1[r].x + vr;
            float si = sgnD * z1[r].y + vi;
            z1[r] = make_float2(sr * wx + si * wy, si * wx - sr * wy);
            float vr2 = __shfl_xor(z2[r].x, h);
            float vi2 = __shfl_xor(z2[r].y, h);
            float sr2 = sgnD * z2[r].x + vr2;
            float si2 = sgnD * z2[r].y + vi2;
            z2[r] = make_float2(sr2 * wx + si2 * wy, si2 * wx - sr2 * wy);
        }
    }

    // ---- epilogue: lane-pair unpack [R9-verified] -> fp16 staging [R22]
    const int laneE = lane & ~1;
    const int RlE = bitrev6(laneE);
    const int lpAp = bitrev6(63 - RlE);
    const int lpBp = bitrev6((64 - RlE) & 63);
    const int SIG[16] = {0, 3, 2, 1, 15, 14, 13, 12, 11, 10, 9, 8, 7, 6, 5, 4};
    const bool isA = !(lane & 1);
    const bool okW1 = isA ? true : v1;
    const bool okW2 = isA ? v2 : v3;
    const int tt1 = 4 * wv + (lane & 1);
    const int tt2 = tt1 + 2;

    unsigned fl1 = 0, fl2 = 0;
    #pragma unroll
    for (int r = 0; r < 16; ++r) {
        const int lp = (r == 0) ? lpBp : lpAp;
        const int rho = ((r & 3) << 2) | (r >> 2);
        const int k = 16 * RlE + rho;
        {
            float ax = __shfl(z1[r].x, laneE);
            float ay = __shfl(z1[r].y, laneE);
            float px = __shfl(z1[SIG[r]].x, lp);
            float py = __shfl(z1[SIG[r]].y, lp);
            float rf  = 0.5f * (isA ? (ax + px) : (ay + py));
            float iff = 0.5f * (isA ? (ay - py) : (px - ax));
            sbuf[slot17(k, tt1)] = __floats2half2_rn(
                sqrtf(rf * rf + iff * iff), fast_atan2f(iff, rf));
            bool fc = (k == 0) ? (__builtin_fabsf(rf) < FLAG_T)
                               : (__builtin_fabsf(iff) < FLAG_T);
            if (okW1 && fc) fl1 |= (1u << r);
        }
        {
            float ax = __shfl(z2[r].x, laneE);
            float ay = __shfl(z2[r].y, laneE);
            float px = __shfl(z2[SIG[r]].x, lp);
            float py = __shfl(z2[SIG[r]].y, lp);
            float rf  = 0.5f * (isA ? (ax + px) : (ay + py));
            float iff = 0.5f * (isA ? (ay - py) : (px - ax));
            sbuf[slot17(k, tt2)] = __floats2half2_rn(
                sqrtf(rf * rf + iff * iff), fast_atan2f(iff, rf));
            bool fc = (k == 0) ? (__builtin_fabsf(rf) < FLAG_T)
                               : (__builtin_fabsf(iff) < FLAG_T);
            if (okW2 && fc) fl2 |= (1u << r);
        }
    }

    // ---- bin 512 (Nyquist): re fp64 pair-diff sums, im exact dots
    if (lane == 1) {
        float a0 = (float)pA, a1 = (float)pB, a2 = (float)pC, a3 = (float)pD;
        sbuf[slot17(512, 4*wv + 0)] = __floats2half2_rn(sqrtf(a0*a0 + IA*IA),
                                                        fast_atan2f(IA, a0));
        sbuf[slot17(512, 4*wv + 1)] = __floats2half2_rn(sqrtf(a1*a1 + IB*IB),
                                                        fast_atan2f(IB, a1));
        sbuf[slot17(512, 4*wv + 2)] = __floats2half2_rn(sqrtf(a2*a2 + IC*IC),
                                                        fast_atan2f(IC, a2));
        sbuf[slot17(512, 4*wv + 3)] = __floats2half2_rn(sqrtf(a3*a3 + ID*ID),
                                                        fast_atan2f(ID, a3));
    }

    // ---- repair pass 1 (FFT1): wave-cooperative exact fp64 dot [R21]
    {
        unsigned long long wm = __ballot(fl1 != 0);
        while (wm) {
            int L = __ffsll((unsigned long long)wm) - 1;
            wm &= wm - 1;
            unsigned flL = __shfl(fl1, L);
            const int kb = 16 * bitrev6(L & ~1);
            const int f  = L & 1;
            const float* px = xptr + f * HOP;
            while (flL) {
                int r = __ffs(flL) - 1;
                flL &= flL - 1;
                int k = kb + (((r & 3) << 2) | (r >> 2));
                double2 cur = wexp64((k * lane) & 1023);
                double2 S   = wexp64((k * 64) & 1023);
                double re = 0.0, im = 0.0;
                #pragma unroll
                for (int j = 0; j < 16; ++j) {
                    int n = 64 * j + lane;
                    double xw = (double)wrow[n] * (double)px[n];
                    re += xw * cur.x;
                    im -= xw * cur.y;
                    double nx = cur.x * S.x - cur.y * S.y;
                    double ny = cur.y * S.x + cur.x * S.y;
                    cur.x = nx; cur.y = ny;
                }
                #pragma unroll
                for (int off = 32; off > 0; off >>= 1) {
                    re += __shfl_xor(re, off);
                    im += __shfl_xor(im, off);
                }
                if (lane == L) {
                    sbuf[slot17(k, 4*wv + f)] = __floats2half2_rn(
                        sqrtf((float)(re * re + im * im)),
                        fast_atan2f((float)im, (float)re));
                }
            }
        }
    }
    // ---- repair pass 2 (FFT2)
    {
        unsigned long long wm = __ballot(fl2 != 0);
        while (wm) {
            int L = __ffsll((unsigned long long)wm) - 1;
            wm &= wm - 1;
            unsigned flL = __shfl(fl2, L);
            const int kb = 16 * bitrev6(L & ~1);
            const int f  = L & 1;
            const float* px = xptr + (2 + f) * HOP;
            while (flL) {
                int r = __ffs(flL) - 1;
                flL &= flL - 1;
                int k = kb + (((r & 3) << 2) | (r >> 2));
                double2 cur = wexp64((k * lane) & 1023);
                double2 S   = wexp64((k * 64) & 1023);
                double re = 0.0, im = 0.0;
                #pragma unroll
                for (int j = 0; j < 16; ++j) {
                    int n = 64 * j + lane;
                    double xw = (double)wrow[n] * (double)px[n];
                    re += xw * cur.x;
                    im -= xw * cur.y;
                    double nx = cur.x * S.x - cur.y * S.y;
                    double ny = cur.y * S.x + cur.x * S.y;
                    cur.x = nx; cur.y = ny;
                }
                #pragma unroll
                for (int off = 32; off > 0; off >>= 1) {
                    re += __shfl_xor(re, off);
                    im += __shfl_xor(im, off);
                }
                if (lane == L) {
                    sbuf[slot17(k, 4*wv + 2 + f)] = __floats2half2_rn(
                        sqrtf((float)(re * re + im * im)),
                        fast_atan2f((float)im, (float)re));
                }
            }
        }
    }

    __syncthreads();

    // ---- flush: 16-t-wide coalesced runs, no batch straddle
    float* omag = out + (size_t)b * CUT * T_FRAMES;
    const size_t PH = (size_t)BATCH * CUT * T_FRAMES;
    for (int f = tid; f < CUT * 16; f += 256) {
        int k = f >> 4, tt = f & 15;
        int t = tb + tt;
        if (t < T_FRAMES) {
            __half2 v = sbuf[slot17(k, tt)];
            size_t g = (size_t)k * T_FRAMES + t;
            omag[g]      = __low2float(v);
            omag[g + PH] = __high2float(v);
        }
    }
}

extern "C" void kernel_launch(void* const* d_in, const int* in_sizes, int n_in,
                              void* d_out, int out_size, void* d_ws, size_t ws_size,
                              hipStream_t stream) {
    (void)in_sizes; (void)n_in; (void)d_ws; (void)ws_size; (void)out_size;
    const float* x     = (const float*)d_in[0];
    const float* basis = (const float*)d_in[1];
    float* out = (float*)d_out;
    dim3 grid(NWG);     // 1024 blocks x 4 waves, 16 frames per block
    dim3 block(256);
    stft_fft_kernel<<<grid, block, 0, stream>>>(x, basis, out);
}

// Round 24
// 54.558 us; speedup vs baseline: 1.2089x; 1.2089x over previous
//
#include <hip/hip_runtime.h>
#include <hip/hip_fp16.h>

#define HOP 256
#define CUT 513
#define T_FRAMES 1021
#define N_SAMPLES 262144
#define BATCH 16
#define NPAIR 511                 // frame pairs per batch (last pair is lone)
#define NWG 2044                  // 8176 wave-tasks / 4 waves per block
#define FLAG_T 0.01f              // phase-risk flag threshold

// 6-bit bit reversal
__device__ __forceinline__ int bitrev6(int v) {
    return ((v & 1) << 5) | ((v & 2) << 3) | ((v & 4) << 1)
         | ((v & 8) >> 1) | ((v & 16) >> 3) | ((v & 32) >> 5);
}
// LDS slot for (k, tt in 0..7): stride 9 + XOR swizzle [R17-verified]
__device__ __forceinline__ int slotOf(int k, int tt) {
    return 9 * k + (tt ^ ((k >> 4) & 7));
}
// W_1024^k as (cos,sin), arg in revolutions [R7-verified]
__device__ __forceinline__ float2 twid(float rev) {
    return make_float2(__builtin_amdgcn_cosf(rev), __builtin_amdgcn_sinf(rev));
}
// fp32 complex helpers (angle-add / angle-double on unit circle) [R9-verified]
__device__ __forceinline__ float2 cmulf(float2 a, float2 b) {
    return make_float2(a.x * b.x - a.y * b.y, a.y * b.x + a.x * b.y);
}
__device__ __forceinline__ float2 csqf(float2 a) {
    return make_float2(a.x * a.x - a.y * a.y, 2.0f * a.x * a.y);
}
__device__ __forceinline__ float2 cmulwf(float yr, float yi, float2 w) {
    return make_float2(yr * w.x + yi * w.y, yi * w.x - yr * w.y);
}
// fast atan2 [R13-verified]
__device__ __forceinline__ float fast_atan2f(float y, float x) {
    const float PI  = 3.14159265358979323846f;
    const float PI2 = 1.57079632679489661923f;
    float ay = __builtin_fabsf(y), ax = __builtin_fabsf(x);
    float mx = fmaxf(ax, ay), mn = fminf(ax, ay);
    float r  = mn * __builtin_amdgcn_rcpf(mx);
    float s  = r * r;
    float p  = r * (0.99997726f + s * (-0.33262347f + s * (0.19354346f
             + s * (-0.11643287f + s * (0.05265332f + s * (-0.01172120f))))));
    p = (ay > ax) ? (PI2 - p) : p;
    p = (x < 0.0f) ? (PI - p) : p;
    return __builtin_copysignf(p, y);
}
// fp64 (cos,sin) of 2*pi*e/1024 [R16-verified]
__device__ __forceinline__ double2 wexp64(int e) {
    const int d = e & 63, c = (e >> 6) & 3, a = (e >> 8) & 3;
    double xx = (6.2831853071795864769252867665590057684 / 1024.0) * (double)d;
    double x2 = xx * xx;
    double cc = 1.0 + x2 * (-0.5 + x2 * (1.0/24.0 + x2 * (-1.0/720.0
               + x2 * (1.0/40320.0 + x2 * (-1.0/3628800.0)))));
    double ss = xx * (1.0 + x2 * (-1.0/6.0 + x2 * (1.0/120.0 + x2 * (-1.0/5040.0
               + x2 * (1.0/362880.0 + x2 * (-1.0/39916800.0))))));
    double kc = (c == 0) ? 1.0
              : (c == 1) ? 0.92387953251128675612818318939679
              : (c == 2) ? 0.70710678118654752440084436210485
                         : 0.38268343236508977172845998403040;
    double ks = (c == 0) ? 0.0
              : (c == 1) ? 0.38268343236508977172845998403040
              : (c == 2) ? 0.70710678118654752440084436210485
                         : 0.92387953251128675612818318939679;
    double cr = cc * kc - ss * ks;
    double ci = ss * kc + cc * ks;
    double2 r;
    r.x = (a == 0) ? cr : ((a == 1) ? -ci : ((a == 2) ? -cr : ci));
    r.y = (a == 0) ? ci : ((a == 1) ?  cr : ((a == 2) ? -ci : -cr));
    return r;
}

__global__ __launch_bounds__(256, 4) void stft_fft_kernel(
    const float* __restrict__ x,
    const float* __restrict__ basis,
    float* __restrict__ out)
{
    // fp16-packed staging (.x = mag, .y = phase) [R22-verified]
    __shared__ __half2 sbuf[9 * CUT + 8];

    const int tid  = threadIdx.x;
    const int lane = tid & 63;
    const int wv   = tid >> 6;

    // bijective XCD-chunked swizzle (NWG % 8 == 4); 4 consecutive pairs/block
    const int q8 = NWG >> 3, rem = NWG & 7;
    const int xcd = blockIdx.x & 7, idx = blockIdx.x >> 3;
    const int sb = (xcd < rem) ? (xcd * (q8 + 1) + idx)
                               : (rem * (q8 + 1) + (xcd - rem) * q8 + idx);
    const int task = sb * 4 + wv;
    const int b  = task / NPAIR;
    const int pr = task - b * NPAIR;
    const int t0 = 2 * pr;
    const bool has_b = (t0 + 1 < T_FRAMES);
    const int ttA = 2 * wv;               // this wave's LDS columns

    const float* xptr = x + (size_t)b * N_SAMPLES + (size_t)t0 * HOP;
    const float* wrow = basis;                          // row 0 == Hann window

    // ---- 8-reg rolling-window load [R21-verified]
    float2 z[16];
    float IA = 0.f, IB = 0.f;
    double pA = 0.0, pB = 0.0;            // per-lane fp64 partial of sum(w*x)
    float xv[8];
    #pragma unroll
    for (int j = 0; j < 8; ++j) xv[j] = xptr[64 * j + lane];
    #pragma unroll
    for (int r = 0; r < 4; ++r) {
        int n = 64 * r + lane;
        float wn = wrow[n];
        float cn = basis[1025 * 1024 + n];
        float xa = xv[r], xb2 = xv[r + 4];
        z[r] = make_float2(wn * xa, wn * xb2);
        IA += cn * xa;  IB += cn * xb2;
        pA += (double)wn * (double)xa;  pB += (double)wn * (double)xb2;
    }
    #pragma unroll
    for (int j = 0; j < 4; ++j) xv[j] = xptr[64 * (8 + j) + lane];     // j=8..11
    #pragma unroll
    for (int r = 4; r < 8; ++r) {
        int n = 64 * r + lane;
        float wn = wrow[n];
        float cn = basis[1025 * 1024 + n];
        float xa = xv[r], xb2 = xv[r - 4];
        z[r] = make_float2(wn * xa, wn * xb2);
        IA += cn * xa;  IB += cn * xb2;
        pA += (double)wn * (double)xa;  pB += (double)wn * (double)xb2;
    }
    #pragma unroll
    for (int j = 4; j < 8; ++j) xv[j] = xptr[64 * (8 + j) + lane];     // j=12..15
    #pragma unroll
    for (int r = 8; r < 12; ++r) {
        int n = 64 * r + lane;
        float wn = wrow[n];
        float cn = basis[1025 * 1024 + n];
        float xa = xv[r - 8], xb2 = xv[r - 4];
        z[r] = make_float2(wn * xa, wn * xb2);
        IA += cn * xa;  IB += cn * xb2;
        pA += (double)wn * (double)xa;  pB += (double)wn * (double)xb2;
    }
    #pragma unroll
    for (int j = 0; j < 4; ++j)           // j=16..19, frame-B only
        xv[j] = has_b ? xptr[64 * (16 + j) + lane] : 0.0f;
    #pragma unroll
    for (int r = 12; r < 16; ++r) {
        int n = 64 * r + lane;
        float wn = wrow[n];
        float cn = basis[1025 * 1024 + n];
        float xa = xv[r - 8], xb2 = xv[r - 12];
        z[r] = make_float2(wn * xa, wn * xb2);
        IA += cn * xa;  IB += cn * xb2;
        pA += (double)wn * (double)xa;  pB += (double)wn * (double)xb2;
    }

    // ---- Nyquist-re via pair-diff reduce [R19-verified]; DC chain DROPPED
    // (k=0 im is exactly +0 via self-partner unpack; |re|<T handled by the
    //  repair path — R23-verified)
    double nrA, nrB;
    {
        double qA = __shfl_xor(pA, 1), qB = __shfl_xor(pB, 1);
        nrA = (lane & 1) ? (qA - pA) : (pA - qA);
        nrB = (lane & 1) ? (qB - pB) : (pB - qB);
        #pragma unroll
        for (int off = 2; off <= 32; off <<= 1) {
            nrA += __shfl_xor(nrA, off); nrB += __shfl_xor(nrB, off);
        }
        #pragma unroll
        for (int off = 32; off > 0; off >>= 1) {
            IA += __shfl_xor(IA, off); IB += __shfl_xor(IB, off);
        }
    }

    // ---- single-trans twiddle base: W^lane (all others by squaring [R9])
    const float2 wl = twid((float)lane * (1.0f / 1024.0f));

    // ---- stage 0: radix-4 DIF, stride 256; twiddles W^{64r0+lane} via
    // exact pi/8 rotation constants (x) wl, then squares [R9-verified form]
    {
        const float KC[4] = { 1.0f, 0.923879532511286756f,
                              0.707106781186547524f, 0.382683432365089772f };
        const float KS[4] = { 0.0f, 0.382683432365089772f,
                              0.707106781186547524f, 0.923879532511286756f };
        #pragma unroll
        for (int r0 = 0; r0 < 4; ++r0) {
            float2 w1 = cmulf(make_float2(KC[r0], KS[r0]), wl);
            float2 w2 = csqf(w1);
            float2 w3 = cmulf(w1, w2);
            float2 A = z[r0], B = z[r0 + 4], C = z[r0 + 8], D = z[r0 + 12];
            float t0r = A.x + C.x, t0i = A.y + C.y, t1r = A.x - C.x, t1i = A.y - C.y;
            float t2r = B.x + D.x, t2i = B.y + D.y, t3r = B.x - D.x, t3i = B.y - D.y;
            z[r0]      = make_float2(t0r + t2r, t0i + t2i);
            z[r0 + 4]  = cmulwf(t1r + t3i, t1i - t3r, w1);
            z[r0 + 8]  = cmulwf(t0r - t2r, t0i - t2i, w2);
            z[r0 + 12] = cmulwf(t1r - t3i, t1i + t3r, w3);
        }
    }

    // ---- stage 1: radix-4 DIF, stride 64; W^{4l},W^{8l},W^{12l} by squaring
    float2 w8;
    {
        float2 w4 = csqf(csqf(wl));
        w8 = csqf(w4);
        float2 w12 = cmulf(w4, w8);
        #pragma unroll
        for (int g = 0; g < 4; ++g) {
            float2 A = z[4*g], B = z[4*g+1], C = z[4*g+2], D = z[4*g+3];
            float t0r = A.x + C.x, t0i = A.y + C.y, t1r = A.x - C.x, t1i = A.y - C.y;
            float t2r = B.x + D.x, t2i = B.y + D.y, t3r = B.x - D.x, t3i = B.y - D.y;
            z[4*g]     = make_float2(t0r + t2r, t0i + t2i);
            z[4*g + 1] = cmulwf(t1r + t3i, t1i - t3r, w4);
            z[4*g + 2] = cmulwf(t0r - t2r, t0i - t2i, w8);
            z[4*g + 3] = cmulwf(t1r - t3i, t1i + t3r, w12);
        }
    }

    // ---- stages 2..7: radix-2 across lanes, branchless; twiddle chain
    // t = W^{(512/h)l} by squaring + (-1)^{l>>(5-st)} sign fix [R9-verified]
    {
        float2 t = csqf(w8);   // W^{16*lane}
        #pragma unroll
        for (int st = 0; st < 6; ++st) {
            const int h = 32 >> st;
            const bool hi = (lane & h) != 0;
            const int sgn = (lane >> (5 - st)) & 1;
            float wx = sgn ? -t.x : t.x;
            float wy = sgn ? -t.y : t.y;
            wx = hi ? wx : 1.0f;
            wy = hi ? wy : 0.0f;
            const float sgnD = hi ? -1.0f : 1.0f;
            #pragma unroll
            for (int r = 0; r < 16; ++r) {
                float vr = __shfl_xor(z[r].x, h);
                float vi = __shfl_xor(z[r].y, h);
                float sr = sgnD * z[r].x + vr;
                float si = sgnD * z[r].y + vi;
                z[r] = make_float2(sr * wx + si * wy, si * wx - sr * wy);
            }
            if (st < 5) t = csqf(t);
        }
    }

    // position (r,lane) holds bin k = 16*bitrev6(lane) + drev4(r).
    // Lane-pair epilogue [R9-verified] -> fp16 staging [R22-verified].
    const int laneE = lane & ~1;
    const int RlE = bitrev6(laneE);               // < 32
    const int lpA = bitrev6(63 - RlE);
    const int lpB = bitrev6((64 - RlE) & 63);
    const int SIG[16] = {0, 3, 2, 1, 15, 14, 13, 12, 11, 10, 9, 8, 7, 6, 5, 4};
    const bool isA = !(lane & 1);
    const bool okW = isA | has_b;
    const int myTT = ttA + (lane & 1);

    unsigned flags = 0;
    #pragma unroll
    for (int r = 0; r < 16; ++r) {
        const int lp = (r == 0) ? lpB : lpA;
        float ax = __shfl(z[r].x, laneE);
        float ay = __shfl(z[r].y, laneE);
        float px = __shfl(z[SIG[r]].x, lp);
        float py = __shfl(z[SIG[r]].y, lp);
        float rr = isA ? (ax + px) : (ay + py);
        float ii = isA ? (ay - py) : (px - ax);
        float rf  = 0.5f * rr;
        float iff = 0.5f * ii;
        const int rho = ((r & 3) << 2) | (r >> 2);
        const int k = 16 * RlE + rho;
        sbuf[slotOf(k, myTT)] = __floats2half2_rn(
            sqrtf(rf * rf + iff * iff), fast_atan2f(iff, rf));
        // k==0: im exactly +0; risk is |re|<T (sign of re) [R23-verified]
        bool fc = (k == 0) ? (__builtin_fabsf(rf) < FLAG_T)
                           : (__builtin_fabsf(iff) < FLAG_T);
        if (okW && fc) flags |= (1u << r);
    }

    // ---- bin 512 (Nyquist): re fp64 pair-diff sum, im exact dots
    if (lane == 1) {
        float rf = (float)nrA, rf2 = (float)nrB;
        sbuf[slotOf(512, ttA)]     = __floats2half2_rn(sqrtf(rf * rf + IA * IA),
                                                       fast_atan2f(IA, rf));
        sbuf[slotOf(512, ttA + 1)] = __floats2half2_rn(sqrtf(rf2 * rf2 + IB * IB),
                                                       fast_atan2f(IB, rf2));
    }

    // ---- repair loop: wave-cooperative exact fp64 dot per flagged bin
    unsigned long long wm = __ballot(flags != 0);
    while (wm) {
        int L = __ffsll((unsigned long long)wm) - 1;
        wm &= wm - 1;
        unsigned flL = __shfl(flags, L);
        const int kb = 16 * bitrev6(L & ~1);
        const int f  = L & 1;
        const float* px = xptr + f * HOP;
        while (flL) {
            int r = __ffs(flL) - 1;
            flL &= flL - 1;
            int k = kb + (((r & 3) << 2) | (r >> 2));
            double2 cur = wexp64((k * lane) & 1023);
            double2 S   = wexp64((k * 64) & 1023);
            double re = 0.0, im = 0.0;
            #pragma unroll
            for (int j = 0; j < 16; ++j) {
                int n = 64 * j + lane;
                double xw = (double)wrow[n] * (double)px[n];
                re += xw * cur.x;
                im -= xw * cur.y;
                double nx = cur.x * S.x - cur.y * S.y;
                double ny = cur.y * S.x + cur.x * S.y;
                cur.x = nx; cur.y = ny;
            }
            #pragma unroll
            for (int off = 32; off > 0; off >>= 1) {
                re += __shfl_xor(re, off);
                im += __shfl_xor(im, off);
            }
            if (lane == L) {
                sbuf[slotOf(k, ttA + f)] = __floats2half2_rn(
                    sqrtf((float)(re * re + im * im)),
                    fast_atan2f((float)im, (float)re));
            }
        }
    }

    __syncthreads();

    // ---- flush: coalesced 8-t-wide runs; per-column (b,t) recomputed
    const size_t PH = (size_t)BATCH * CUT * T_FRAMES;
    for (int f = tid; f < CUT * 8; f += 256) {
        int k = f >> 3, ttx = f & 7;
        int task_w = sb * 4 + (ttx >> 1);
        int bw  = task_w / NPAIR;
        int prw = task_w - bw * NPAIR;
        int tw  = 2 * prw + (ttx & 1);
        if (tw < T_FRAMES) {
            __half2 v = sbuf[slotOf(k, ttx)];
            size_t g = (size_t)bw * CUT * T_FRAMES + (size_t)k * T_FRAMES + tw;
            out[g]      = __low2float(v);
            out[g + PH] = __high2float(v);
        }
    }
}

extern "C" void kernel_launch(void* const* d_in, const int* in_sizes, int n_in,
                              void* d_out, int out_size, void* d_ws, size_t ws_size,
                              hipStream_t stream) {
    (void)in_sizes; (void)n_in; (void)d_ws; (void)ws_size; (void)out_size;
    const float* x     = (const float*)d_in[0];
    const float* basis = (const float*)d_in[1];
    float* out = (float*)d_out;
    dim3 grid(NWG);     // 2044 blocks x 4 waves
    dim3 block(256);
    stft_fft_kernel<<<grid, block, 0, stream>>>(x, basis, out);
}

// Round 25
// 53.313 us; speedup vs baseline: 1.2372x; 1.0234x over previous
//
#include <hip/hip_runtime.h>
#include <hip/hip_fp16.h>

#define HOP 256
#define CUT 513
#define T_FRAMES 1021
#define N_SAMPLES 262144
#define BATCH 16
#define NPAIR 511                 // frame pairs per batch (last pair is lone)
#define NWG 2044                  // 8176 wave-tasks / 4 waves per block
#define FLAG_T 0.01f              // phase-risk flag threshold

// 6-bit bit reversal
__device__ __forceinline__ int bitrev6(int v) {
    return ((v & 1) << 5) | ((v & 2) << 3) | ((v & 4) << 1)
         | ((v & 8) >> 1) | ((v & 16) >> 3) | ((v & 32) >> 5);
}
// LDS slot for (k, tt in 0..7): stride 9 + XOR swizzle [R17-verified]
__device__ __forceinline__ int slotOf(int k, int tt) {
    return 9 * k + (tt ^ ((k >> 4) & 7));
}
// W_1024^k as (cos,sin), arg in revolutions [R7-verified]
__device__ __forceinline__ float2 twid(float rev) {
    return make_float2(__builtin_amdgcn_cosf(rev), __builtin_amdgcn_sinf(rev));
}
// fp32 complex helpers [R9/R24-verified]
__device__ __forceinline__ float2 cmulf(float2 a, float2 b) {
    return make_float2(a.x * b.x - a.y * b.y, a.y * b.x + a.x * b.y);
}
__device__ __forceinline__ float2 csqf(float2 a) {
    return make_float2(a.x * a.x - a.y * a.y, 2.0f * a.x * a.y);
}
__device__ __forceinline__ float2 cmulwf(float yr, float yi, float2 w) {
    return make_float2(yr * w.x + yi * w.y, yi * w.x - yr * w.y);
}
// DPP lane-permute on the VALU pipe (frees the shared per-CU DS unit).
// 0xB1 = quad_perm[1,0,3,2] (xor1); 0x4E = quad_perm[2,3,0,1] (xor2);
// 0x128 = row_ror:8 (== xor8 within 16-lane rows); 0xA0 = quad_perm[0,0,2,2]
// (pair-even broadcast, == shfl to lane&~1).
template <int CTRL>
__device__ __forceinline__ float dppf(float v) {
    return __int_as_float(__builtin_amdgcn_mov_dpp(
        __float_as_int(v), CTRL, 0xF, 0xF, false));
}
// fast atan2 [R13-verified]
__device__ __forceinline__ float fast_atan2f(float y, float x) {
    const float PI  = 3.14159265358979323846f;
    const float PI2 = 1.57079632679489661923f;
    float ay = __builtin_fabsf(y), ax = __builtin_fabsf(x);
    float mx = fmaxf(ax, ay), mn = fminf(ax, ay);
    float r  = mn * __builtin_amdgcn_rcpf(mx);
    float s  = r * r;
    float p  = r * (0.99997726f + s * (-0.33262347f + s * (0.19354346f
             + s * (-0.11643287f + s * (0.05265332f + s * (-0.01172120f))))));
    p = (ay > ax) ? (PI2 - p) : p;
    p = (x < 0.0f) ? (PI - p) : p;
    return __builtin_copysignf(p, y);
}
// fp64 (cos,sin) of 2*pi*e/1024 [R16-verified]
__device__ __forceinline__ double2 wexp64(int e) {
    const int d = e & 63, c = (e >> 6) & 3, a = (e >> 8) & 3;
    double xx = (6.2831853071795864769252867665590057684 / 1024.0) * (double)d;
    double x2 = xx * xx;
    double cc = 1.0 + x2 * (-0.5 + x2 * (1.0/24.0 + x2 * (-1.0/720.0
               + x2 * (1.0/40320.0 + x2 * (-1.0/3628800.0)))));
    double ss = xx * (1.0 + x2 * (-1.0/6.0 + x2 * (1.0/120.0 + x2 * (-1.0/5040.0
               + x2 * (1.0/362880.0 + x2 * (-1.0/39916800.0))))));
    double kc = (c == 0) ? 1.0
              : (c == 1) ? 0.92387953251128675612818318939679
              : (c == 2) ? 0.70710678118654752440084436210485
                         : 0.38268343236508977172845998403040;
    double ks = (c == 0) ? 0.0
              : (c == 1) ? 0.38268343236508977172845998403040
              : (c == 2) ? 0.70710678118654752440084436210485
                         : 0.92387953251128675612818318939679;
    double cr = cc * kc - ss * ks;
    double ci = ss * kc + cc * ks;
    double2 r;
    r.x = (a == 0) ? cr : ((a == 1) ? -ci : ((a == 2) ? -cr : ci));
    r.y = (a == 0) ? ci : ((a == 1) ?  cr : ((a == 2) ? -ci : -cr));
    return r;
}

// radix-2 cross-lane DIF stage; exchange expressions are macro args so the
// transport (bpermute vs DPP) varies while the verified math stays identical
#define RADIX2_STAGE(ST, H, XCHX, XCHY)                                   \
    {                                                                     \
        const bool hi = (lane & (H)) != 0;                                \
        const int sgn = (lane >> (5 - (ST))) & 1;                         \
        float wx = sgn ? -t.x : t.x;                                      \
        float wy = sgn ? -t.y : t.y;                                      \
        wx = hi ? wx : 1.0f;                                              \
        wy = hi ? wy : 0.0f;                                              \
        const float sgnD = hi ? -1.0f : 1.0f;                             \
        _Pragma("unroll")                                                 \
        for (int r = 0; r < 16; ++r) {                                    \
            float vr = XCHX;                                              \
            float vi = XCHY;                                              \
            float sr = sgnD * z[r].x + vr;                                \
            float si = sgnD * z[r].y + vi;                                \
            z[r] = make_float2(sr * wx + si * wy, si * wx - sr * wy);     \
        }                                                                 \
    }

__global__ __launch_bounds__(256, 4) void stft_fft_kernel(
    const float* __restrict__ x,
    const float* __restrict__ basis,
    float* __restrict__ out)
{
    // fp16-packed staging (.x = mag, .y = phase) [R22-verified]
    __shared__ __half2 sbuf[9 * CUT + 8];

    const int tid  = threadIdx.x;
    const int lane = tid & 63;
    const int wv   = tid >> 6;

    // bijective XCD-chunked swizzle (NWG % 8 == 4); 4 consecutive pairs/block
    const int q8 = NWG >> 3, rem = NWG & 7;
    const int xcd = blockIdx.x & 7, idx = blockIdx.x >> 3;
    const int sb = (xcd < rem) ? (xcd * (q8 + 1) + idx)
                               : (rem * (q8 + 1) + (xcd - rem) * q8 + idx);
    const int task = sb * 4 + wv;
    const int b  = task / NPAIR;
    const int pr = task - b * NPAIR;
    const int t0 = 2 * pr;
    const bool has_b = (t0 + 1 < T_FRAMES);
    const int ttA = 2 * wv;               // this wave's LDS columns

    const float* xptr = x + (size_t)b * N_SAMPLES + (size_t)t0 * HOP;
    const float* wrow = basis;                          // row 0 == Hann window

    // ---- 8-reg rolling-window load [R21-verified]
    float2 z[16];
    float IA = 0.f, IB = 0.f;
    double pA = 0.0, pB = 0.0;            // per-lane fp64 partial of sum(w*x)
    float xv[8];
    #pragma unroll
    for (int j = 0; j < 8; ++j) xv[j] = xptr[64 * j + lane];
    #pragma unroll
    for (int r = 0; r < 4; ++r) {
        int n = 64 * r + lane;
        float wn = wrow[n];
        float cn = basis[1025 * 1024 + n];
        float xa = xv[r], xb2 = xv[r + 4];
        z[r] = make_float2(wn * xa, wn * xb2);
        IA += cn * xa;  IB += cn * xb2;
        pA += (double)wn * (double)xa;  pB += (double)wn * (double)xb2;
    }
    #pragma unroll
    for (int j = 0; j < 4; ++j) xv[j] = xptr[64 * (8 + j) + lane];     // j=8..11
    #pragma unroll
    for (int r = 4; r < 8; ++r) {
        int n = 64 * r + lane;
        float wn = wrow[n];
        float cn = basis[1025 * 1024 + n];
        float xa = xv[r], xb2 = xv[r - 4];
        z[r] = make_float2(wn * xa, wn * xb2);
        IA += cn * xa;  IB += cn * xb2;
        pA += (double)wn * (double)xa;  pB += (double)wn * (double)xb2;
    }
    #pragma unroll
    for (int j = 4; j < 8; ++j) xv[j] = xptr[64 * (8 + j) + lane];     // j=12..15
    #pragma unroll
    for (int r = 8; r < 12; ++r) {
        int n = 64 * r + lane;
        float wn = wrow[n];
        float cn = basis[1025 * 1024 + n];
        float xa = xv[r - 8], xb2 = xv[r - 4];
        z[r] = make_float2(wn * xa, wn * xb2);
        IA += cn * xa;  IB += cn * xb2;
        pA += (double)wn * (double)xa;  pB += (double)wn * (double)xb2;
    }
    #pragma unroll
    for (int j = 0; j < 4; ++j)           // j=16..19, frame-B only
        xv[j] = has_b ? xptr[64 * (16 + j) + lane] : 0.0f;
    #pragma unroll
    for (int r = 12; r < 16; ++r) {
        int n = 64 * r + lane;
        float wn = wrow[n];
        float cn = basis[1025 * 1024 + n];
        float xa = xv[r - 8], xb2 = xv[r - 12];
        z[r] = make_float2(wn * xa, wn * xb2);
        IA += cn * xa;  IB += cn * xb2;
        pA += (double)wn * (double)xa;  pB += (double)wn * (double)xb2;
    }

    // ---- Nyquist-re via pair-diff reduce [R19-verified]; DC chain dropped
    double nrA, nrB;
    {
        double qA = __shfl_xor(pA, 1), qB = __shfl_xor(pB, 1);
        nrA = (lane & 1) ? (qA - pA) : (pA - qA);
        nrB = (lane & 1) ? (qB - pB) : (pB - qB);
        #pragma unroll
        for (int off = 2; off <= 32; off <<= 1) {
            nrA += __shfl_xor(nrA, off); nrB += __shfl_xor(nrB, off);
        }
        #pragma unroll
        for (int off = 32; off > 0; off >>= 1) {
            IA += __shfl_xor(IA, off); IB += __shfl_xor(IB, off);
        }
    }

    // ---- single-trans twiddle base: W^lane (others by squaring [R24])
    const float2 wl = twid((float)lane * (1.0f / 1024.0f));

    // ---- stage 0: radix-4 DIF, stride 256 [R24-verified]
    {
        const float KC[4] = { 1.0f, 0.923879532511286756f,
                              0.707106781186547524f, 0.382683432365089772f };
        const float KS[4] = { 0.0f, 0.382683432365089772f,
                              0.707106781186547524f, 0.923879532511286756f };
        #pragma unroll
        for (int r0 = 0; r0 < 4; ++r0) {
            float2 w1 = cmulf(make_float2(KC[r0], KS[r0]), wl);
            float2 w2 = csqf(w1);
            float2 w3 = cmulf(w1, w2);
            float2 A = z[r0], B = z[r0 + 4], C = z[r0 + 8], D = z[r0 + 12];
            float t0r = A.x + C.x, t0i = A.y + C.y, t1r = A.x - C.x, t1i = A.y - C.y;
            float t2r = B.x + D.x, t2i = B.y + D.y, t3r = B.x - D.x, t3i = B.y - D.y;
            z[r0]      = make_float2(t0r + t2r, t0i + t2i);
            z[r0 + 4]  = cmulwf(t1r + t3i, t1i - t3r, w1);
            z[r0 + 8]  = cmulwf(t0r - t2r, t0i - t2i, w2);
            z[r0 + 12] = cmulwf(t1r - t3i, t1i + t3r, w3);
        }
    }

    // ---- stage 1: radix-4 DIF, stride 64 [R24-verified]
    float2 w8;
    {
        float2 w4 = csqf(csqf(wl));
        w8 = csqf(w4);
        float2 w12 = cmulf(w4, w8);
        #pragma unroll
        for (int g = 0; g < 4; ++g) {
            float2 A = z[4*g], B = z[4*g+1], C = z[4*g+2], D = z[4*g+3];
            float t0r = A.x + C.x, t0i = A.y + C.y, t1r = A.x - C.x, t1i = A.y - C.y;
            float t2r = B.x + D.x, t2i = B.y + D.y, t3r = B.x - D.x, t3i = B.y - D.y;
            z[4*g]     = make_float2(t0r + t2r, t0i + t2i);
            z[4*g + 1] = cmulwf(t1r + t3i, t1i - t3r, w4);
            z[4*g + 2] = cmulwf(t0r - t2r, t0i - t2i, w8);
            z[4*g + 3] = cmulwf(t1r - t3i, t1i + t3r, w12);
        }
    }

    // ---- stages 2..7: radix-2 across lanes; h=8,2,1 exchanged via DPP
    // (VALU pipe), h=32,16,4 via bpermute. Math identical [R24-verified].
    {
        float2 t = csqf(w8);   // W^{16*lane}
        RADIX2_STAGE(0, 32, __shfl_xor(z[r].x, 32), __shfl_xor(z[r].y, 32))
        t = csqf(t);
        RADIX2_STAGE(1, 16, __shfl_xor(z[r].x, 16), __shfl_xor(z[r].y, 16))
        t = csqf(t);
        RADIX2_STAGE(2, 8, dppf<0x128>(z[r].x), dppf<0x128>(z[r].y))
        t = csqf(t);
        RADIX2_STAGE(3, 4, __shfl_xor(z[r].x, 4), __shfl_xor(z[r].y, 4))
        t = csqf(t);
        RADIX2_STAGE(4, 2, dppf<0x4E>(z[r].x), dppf<0x4E>(z[r].y))
        t = csqf(t);
        RADIX2_STAGE(5, 1, dppf<0xB1>(z[r].x), dppf<0xB1>(z[r].y))
    }

    // position (r,lane) holds bin k = 16*bitrev6(lane) + drev4(r).
    // Lane-pair epilogue [R9-verified]; pair-even broadcast via DPP 0xA0.
    const int laneE = lane & ~1;
    const int RlE = bitrev6(laneE);               // < 32
    const int lpA = bitrev6(63 - RlE);
    const int lpB = bitrev6((64 - RlE) & 63);
    const int SIG[16] = {0, 3, 2, 1, 15, 14, 13, 12, 11, 10, 9, 8, 7, 6, 5, 4};
    const bool isA = !(lane & 1);
    const bool okW = isA | has_b;
    const int myTT = ttA + (lane & 1);

    unsigned flags = 0;
    #pragma unroll
    for (int r = 0; r < 16; ++r) {
        const int lp = (r == 0) ? lpB : lpA;
        float ax = dppf<0xA0>(z[r].x);
        float ay = dppf<0xA0>(z[r].y);
        float px = __shfl(z[SIG[r]].x, lp);
        float py = __shfl(z[SIG[r]].y, lp);
        float rr = isA ? (ax + px) : (ay + py);
        float ii = isA ? (ay - py) : (px - ax);
        float rf  = 0.5f * rr;
        float iff = 0.5f * ii;
        const int rho = ((r & 3) << 2) | (r >> 2);
        const int k = 16 * RlE + rho;
        sbuf[slotOf(k, myTT)] = __floats2half2_rn(
            sqrtf(rf * rf + iff * iff), fast_atan2f(iff, rf));
        // k==0: im exactly +0; risk is |re|<T [R23-verified]
        bool fc = (k == 0) ? (__builtin_fabsf(rf) < FLAG_T)
                           : (__builtin_fabsf(iff) < FLAG_T);
        if (okW && fc) flags |= (1u << r);
    }

    // ---- bin 512 (Nyquist): re fp64 pair-diff sum, im exact dots
    if (lane == 1) {
        float rf = (float)nrA, rf2 = (float)nrB;
        sbuf[slotOf(512, ttA)]     = __floats2half2_rn(sqrtf(rf * rf + IA * IA),
                                                       fast_atan2f(IA, rf));
        sbuf[slotOf(512, ttA + 1)] = __floats2half2_rn(sqrtf(rf2 * rf2 + IB * IB),
                                                       fast_atan2f(IB, rf2));
    }

    // ---- repair loop: wave-cooperative exact fp64 dot per flagged bin
    unsigned long long wm = __ballot(flags != 0);
    while (wm) {
        int L = __ffsll((unsigned long long)wm) - 1;
        wm &= wm - 1;
        unsigned flL = __shfl(flags, L);
        const int kb = 16 * bitrev6(L & ~1);
        const int f  = L & 1;
        const float* px = xptr + f * HOP;
        while (flL) {
            int r = __ffs(flL) - 1;
            flL &= flL - 1;
            int k = kb + (((r & 3) << 2) | (r >> 2));
            double2 cur = wexp64((k * lane) & 1023);
            double2 S   = wexp64((k * 64) & 1023);
            double re = 0.0, im = 0.0;
            #pragma unroll
            for (int j = 0; j < 16; ++j) {
                int n = 64 * j + lane;
                double xw = (double)wrow[n] * (double)px[n];
                re += xw * cur.x;
                im -= xw * cur.y;
                double nx = cur.x * S.x - cur.y * S.y;
                double ny = cur.y * S.x + cur.x * S.y;
                cur.x = nx; cur.y = ny;
            }
            #pragma unroll
            for (int off = 32; off > 0; off >>= 1) {
                re += __shfl_xor(re, off);
                im += __shfl_xor(im, off);
            }
            if (lane == L) {
                sbuf[slotOf(k, ttA + f)] = __floats2half2_rn(
                    sqrtf((float)(re * re + im * im)),
                    fast_atan2f((float)im, (float)re));
            }
        }
    }

    __syncthreads();

    // ---- flush: coalesced 8-t-wide runs; per-column (b,t) recomputed
    const size_t PH = (size_t)BATCH * CUT * T_FRAMES;
    for (int f = tid; f < CUT * 8; f += 256) {
        int k = f >> 3, ttx = f & 7;
        int task_w = sb * 4 + (ttx >> 1);
        int bw  = task_w / NPAIR;
        int prw = task_w - bw * NPAIR;
        int tw  = 2 * prw + (ttx & 1);
        if (tw < T_FRAMES) {
            __half2 v = sbuf[slotOf(k, ttx)];
            size_t g = (size_t)bw * CUT * T_FRAMES + (size_t)k * T_FRAMES + tw;
            out[g]      = __low2float(v);
            out[g + PH] = __high2float(v);
        }
    }
}

extern "C" void kernel_launch(void* const* d_in, const int* in_sizes, int n_in,
                              void* d_out, int out_size, void* d_ws, size_t ws_size,
                              hipStream_t stream) {
    (void)in_sizes; (void)n_in; (void)d_ws; (void)ws_size; (void)out_size;
    const float* x     = (const float*)d_in[0];
    const float* basis = (const float*)d_in[1];
    float* out = (float*)d_out;
    dim3 grid(NWG);     // 2044 blocks x 4 waves
    dim3 block(256);
    stft_fft_kernel<<<grid, block, 0, stream>>>(x, basis, out);
}